// Round 4
// baseline (828.557 us; speedup 1.0000x reference)
//
#include <hip/hip_runtime.h>
#include <cstdint>

typedef __attribute__((ext_vector_type(8))) __bf16 bf16x8;
typedef __attribute__((ext_vector_type(4))) __bf16 bf16x4;
typedef __attribute__((ext_vector_type(4))) float f32x4;

__device__ __forceinline__ void gld_lds16(const void* g, void* l) {
  __builtin_amdgcn_global_load_lds(
      (const __attribute__((address_space(1))) void*)g,
      (__attribute__((address_space(3))) void*)l, 16, 0, 0);
}

__device__ __forceinline__ float block_sum(float v, float* scr) {
#pragma unroll
  for (int off = 32; off > 0; off >>= 1) v += __shfl_down(v, off, 64);
  const int w = threadIdx.x >> 6;
  __syncthreads();
  if ((threadIdx.x & 63) == 0) scr[w] = v;
  __syncthreads();
  float s = 0.f;
  const int nw = blockDim.x >> 6;
  for (int i = 0; i < nw; ++i) s += scr[i];
  return s;
}

__device__ __forceinline__ float gelu_exact(float x) {
  return 0.5f * x * (1.f + erff(x * 0.70710678118654752f));
}

// ---------------- casts ----------------
__global__ __launch_bounds__(256) void k_cast_bf16(const float* __restrict__ in,
                                                   __bf16* __restrict__ out) {
  const long i = ((long)blockIdx.x * 256 + threadIdx.x) * 4;
  f32x4 v = *(const f32x4*)(in + i);
  bf16x4 o = {(__bf16)v[0], (__bf16)v[1], (__bf16)v[2], (__bf16)v[3]};
  *(bf16x4*)(out + i) = o;
}

__global__ __launch_bounds__(256) void k_cast_pad(const float* __restrict__ in,
                                                  __bf16* __restrict__ out,
                                                  int rows_real, int cols) {
  const long i = ((long)blockIdx.x * 256 + threadIdx.x) * 4;
  const int row = (int)(i / cols);
  const int col = (int)(i % cols);
  bf16x4 o;
  if (row < rows_real) {
    f32x4 v = *(const f32x4*)(in + (long)row * cols + col);
    o = (bf16x4){(__bf16)v[0], (__bf16)v[1], (__bf16)v[2], (__bf16)v[3]};
  } else {
    o = (bf16x4){(__bf16)0.f, (__bf16)0.f, (__bf16)0.f, (__bf16)0.f};
  }
  *(bf16x4*)(out + i) = o;
}

// ---------------- GEMM: C = A @ B^T + bias ----------------
// EPI: 0 = f32 store, 1 = bf16 store, 4 = fused self-mod update
template <int EPI>
__global__ __launch_bounds__(256) void k_gemm_bt(
    const __bf16* __restrict__ A, const __bf16* __restrict__ B,
    const float* __restrict__ bias, void* __restrict__ Cout,
    int M, int N, int K, int Nreal,
    float* __restrict__ supR, float* __restrict__ supI) {
  __shared__ __align__(16) __bf16 As[2][128 * 32];
  __shared__ __align__(16) __bf16 Bs[2][128 * 32];
  const int tid = threadIdx.x;
  const int lane = tid & 63;
  const int wid = tid >> 6;
  const int wr = wid >> 1, wc = wid & 1;      // 2x2 wave grid, 64x64 each

  const int gx = gridDim.x, gy = gridDim.y;
  const int nwg = gx * gy;
  int bx, by;
  if ((nwg & 7) == 0) {
    const int lin = blockIdx.y * gx + blockIdx.x;
    const int cpx = nwg >> 3;
    const int w = (lin & 7) * cpx + (lin >> 3);
    bx = w / gy;
    by = w % gy;
  } else {
    bx = blockIdx.x;
    by = blockIdx.y;
  }
  const int m0 = by * 128;
  const int n0 = bx * 128;
  const int frow = lane & 15;
  const int fk = (lane >> 4) * 8;
  f32x4 acc[4][4] = {};

  auto stage = [&](int buf, int k0) {
    const __bf16* Ab = A + (long)m0 * K + k0;
    const __bf16* Bb = B + (long)n0 * K + k0;
#pragma unroll
    for (int q = 0; q < 2; ++q) {
      const int idx = q * 256 + tid;
      const int row = idx >> 2;
      const int col = (idx & 3) * 8;
      gld_lds16(Ab + (long)row * K + col, (char*)(&As[buf][0]) + idx * 16);
      gld_lds16(Bb + (long)row * K + col, (char*)(&Bs[buf][0]) + idx * 16);
    }
  };

  const int nt = K >> 5;  // K/32 tiles
  int cur = 0;
  stage(0, 0);
  __syncthreads();
  for (int t = 0; t < nt; ++t) {
    if (t + 1 < nt) stage(cur ^ 1, (t + 1) << 5);
    bf16x8 af[4], bfr[4];
#pragma unroll
    for (int i = 0; i < 4; ++i) {
      af[i] = *(const bf16x8*)(&As[cur][0] + (wr * 64 + i * 16 + frow) * 32 + fk);
      bfr[i] = *(const bf16x8*)(&Bs[cur][0] + (wc * 64 + i * 16 + frow) * 32 + fk);
    }
#pragma unroll
    for (int im = 0; im < 4; ++im)
#pragma unroll
      for (int in = 0; in < 4; ++in)
        acc[im][in] = __builtin_amdgcn_mfma_f32_16x16x32_bf16(af[im], bfr[in],
                                                              acc[im][in], 0, 0, 0);
    __syncthreads();
    cur ^= 1;
  }

  const int crow0 = m0 + wr * 64 + (lane >> 4) * 4;
  const int ccol0 = n0 + wc * 64 + (lane & 15);
#pragma unroll
  for (int in = 0; in < 4; ++in) {
    const int col = ccol0 + in * 16;
    if (col >= Nreal) continue;
    const float bv = bias[col];
#pragma unroll
    for (int im = 0; im < 4; ++im) {
#pragma unroll
      for (int r = 0; r < 4; ++r) {
        const long row = crow0 + im * 16 + r;
        const float v = acc[im][in][r] + bv;
        if (EPI == 0) {
          ((float*)Cout)[row * Nreal + col] = v;
        } else if (EPI == 1) {
          ((__bf16*)Cout)[row * Nreal + col] = (__bf16)v;
        } else {
          const float gmul = 1.f / (1.f + expf(-v)) + 0.1f;
          const long ix = row * Nreal + col;
          supR[ix] *= gmul;
          supI[ix] *= gmul;
        }
      }
    }
  }
}

// ---------------- LN (over 1024) + exact gelu -> bf16 ----------------
__global__ __launch_bounds__(256) void k_ln_gelu(const float* __restrict__ y,
                                                 const float* __restrict__ g,
                                                 const float* __restrict__ b,
                                                 __bf16* __restrict__ h) {
  __shared__ float scr[8];
  const int tid = threadIdx.x;
  const long row = blockIdx.x;
  const float* yr = y + row * 1024;
  f32x4 v = *(const f32x4*)(yr + tid * 4);
  float ls = v[0] + v[1] + v[2] + v[3];
  const float mu = block_sum(ls, scr) * (1.f / 1024.f);
  float lss = 0.f;
#pragma unroll
  for (int j = 0; j < 4; ++j) {
    const float d = v[j] - mu;
    lss += d * d;
  }
  const float var = block_sum(lss, scr) * (1.f / 1024.f);
  const float rstd = rsqrtf(var + 1e-5f);
  bf16x4 o;
#pragma unroll
  for (int j = 0; j < 4; ++j) {
    const int c = tid * 4 + j;
    const float t = (v[j] - mu) * rstd * g[c] + b[c];
    o[j] = (__bf16)gelu_exact(t);
  }
  *(bf16x4*)(h + row * 1024 + tid * 4) = o;
}

// ---------------- stage C ----------------
__global__ __launch_bounds__(256) void k_stage_c(
    const __bf16* __restrict__ outb, const float* __restrict__ ln_g,
    const float* __restrict__ ln_b, const float* __restrict__ phases,
    const float* __restrict__ temp, float* __restrict__ supr,
    float* __restrict__ supi, int b0) {
  __shared__ float wrs[3][1024];
  __shared__ float wis[3][1024];
  __shared__ float gbuf[2048];
  __shared__ float scr[8];
  const int tid = threadIdx.x;
  const long b = blockIdx.x;

#pragma unroll 1
  for (int s = 0; s < 3; ++s) {
    const __bf16* src = outb + b * 6144 + s * 2048;
    bf16x8 v8 = *(const bf16x8*)(src + tid * 8);
    float x[8];
#pragma unroll
    for (int j = 0; j < 8; ++j) x[j] = (float)v8[j];
    float ls = 0.f;
#pragma unroll
    for (int j = 0; j < 8; ++j) ls += x[j];
    const float mu = block_sum(ls, scr) * (1.f / 2048.f);
    float lss = 0.f;
#pragma unroll
    for (int j = 0; j < 8; ++j) {
      const float d = x[j] - mu;
      lss += d * d;
    }
    const float var = block_sum(lss, scr) * (1.f / 2048.f);
    const float rstd = rsqrtf(var + 1e-5f);
    const float* lg = ln_g + s * 2048;
    const float* lb = ln_b + s * 2048;
    float nsq = 0.f;
#pragma unroll
    for (int j = 0; j < 8; ++j) {
      const int e = tid * 8 + j;
      const float yv = (x[j] - mu) * rstd * lg[e] + lb[e];
      const float gv = expf(-yv * yv);
      gbuf[e] = gv;
      nsq += gv * gv;
    }
    const float normsq = block_sum(nsq, scr) + 1e-8f; // syncs make gbuf visible
    const float factor = sqrtf(2.25f / normsq);
    const float ph = phases[s];
    const float cs = cosf(ph), sn = sinf(ph);
#pragma unroll
    for (int j = 0; j < 4; ++j) {
      const int h = j * 256 + tid;
      const float a = gbuf[h] * factor;
      const float bb = gbuf[h + 1024] * factor;
      wrs[s][h] = a * cs - bb * sn;
      wis[s][h] = a * sn + bb * cs;
    }
    __syncthreads();
  }

  float mr[4];
  float pmn = 0.f;
#pragma unroll
  for (int j = 0; j < 4; ++j) {
    const int h = j * 256 + tid;
    const float m = (wrs[0][h] + wrs[1][h] + wrs[2][h]) * (1.f / 3.f);
    mr[j] = m;
    pmn += m * m;
  }
  const float mnorm = sqrtf(block_sum(pmn, scr)) + 1e-8f;
  float csim[3];
#pragma unroll 1
  for (int s = 0; s < 3; ++s) {
    float pd = 0.f, pw = 0.f;
#pragma unroll
    for (int j = 0; j < 4; ++j) {
      const int h = j * 256 + tid;
      const float w = wrs[s][h];
      pd += w * mr[j];
      pw += w * w;
    }
    const float dot = block_sum(pd, scr);
    const float wn = sqrtf(block_sum(pw, scr)) + 1e-8f;
    csim[s] = dot / (wn * mnorm);
  }
  const float T = temp[0];
  const float t0 = csim[0] / T, t1 = csim[1] / T, t2 = csim[2] / T;
  const float mx = fmaxf(t0, fmaxf(t1, t2));
  const float e0 = expf(t0 - mx), e1 = expf(t1 - mx), e2 = expf(t2 - mx);
  const float inv = 1.f / (e0 + e1 + e2);
  const float w0 = e0 * inv, w1 = e1 * inv, w2 = e2 * inv;
#pragma unroll
  for (int j = 0; j < 4; ++j) {
    const int h = j * 256 + tid;
    supr[(long)(b0 + b) * 1024 + h] = wrs[0][h] * w0 + wrs[1][h] * w1 + wrs[2][h] * w2;
    supi[(long)(b0 + b) * 1024 + h] = wis[0][h] * w0 + wis[1][h] * w1 + wis[2][h] * w2;
  }
}

// ---------------- mag ----------------
__global__ __launch_bounds__(256) void k_mag(const float* __restrict__ sr,
                                             const float* __restrict__ si,
                                             __bf16* __restrict__ mag) {
  const long i = ((long)blockIdx.x * 256 + threadIdx.x) * 4;
  f32x4 r = *(const f32x4*)(sr + i);
  f32x4 im = *(const f32x4*)(si + i);
  bf16x4 o;
#pragma unroll
  for (int j = 0; j < 4; ++j)
    o[j] = (__bf16)sqrtf(r[j] * r[j] + im[j] * im[j] + 1e-8f);
  *(bf16x4*)(mag + i) = o;
}

// ---------------- fused top-8 + sparse cls_w1 -> hid (bf16) ----------------
// One block per batch row. Two-stage reg-resident selection, then
// hid[o] = gelu(b1[o] + sum_k p_k * w1[o, idx_k])  (8-sparse matmul from L2).
__global__ __launch_bounds__(256) void k_topk_cls1(
    const float* __restrict__ supr, const float* __restrict__ supi,
    const float* __restrict__ w1, const float* __restrict__ b1,
    __bf16* __restrict__ hid) {
  __shared__ float candv[32];
  __shared__ int candi[32];
  __shared__ float selv[8];
  __shared__ int seli[8];
  __shared__ float ssum_s;
  const int tid = threadIdx.x;
  const int lane = tid & 63;
  const int wv = tid >> 6;
  const long b = blockIdx.x;

  f32x4 r = *(const f32x4*)(supr + b * 1024 + tid * 4);
  f32x4 im = *(const f32x4*)(supi + b * 1024 + tid * 4);
  float myv[4];
#pragma unroll
  for (int j = 0; j < 4; ++j) myv[j] = r[j] * r[j] + im[j] * im[j];

  // stage 1: per-wave top-8 (no barriers)
  float wcv[8];
  int wch[8];
#pragma unroll 1
  for (int it = 0; it < 8; ++it) {
    float bv = -1.f;
    int bh = 1 << 30;
#pragma unroll
    for (int j = 0; j < 4; ++j)
      if (myv[j] > bv) { bv = myv[j]; bh = tid * 4 + j; }
#pragma unroll
    for (int m = 1; m < 64; m <<= 1) {
      const float ov = __shfl_xor(bv, m, 64);
      const int oh = __shfl_xor(bh, m, 64);
      if (ov > bv || (ov == bv && oh < bh)) { bv = ov; bh = oh; }
    }
    wcv[it] = bv;
    wch[it] = bh;
    const int jj = bh - tid * 4;
    if (jj >= 0 && jj < 4) myv[jj] = -1.f;
  }
  if (lane < 8) {
    candv[wv * 8 + lane] = wcv[lane];
    candi[wv * 8 + lane] = wch[lane];
  }
  __syncthreads();

  // stage 2: wave 0 merges 32 candidates -> top-8
  if (wv == 0) {
    float cv = (lane < 32) ? candv[lane] : -1.f;
    int ch = (lane < 32) ? candi[lane] : (1 << 30);
    float ssum = 0.f;
#pragma unroll 1
    for (int it = 0; it < 8; ++it) {
      float bv = cv;
      int bh = ch;
#pragma unroll
      for (int m = 1; m < 64; m <<= 1) {
        const float ov = __shfl_xor(bv, m, 64);
        const int oh = __shfl_xor(bh, m, 64);
        if (ov > bv || (ov == bv && oh < bh)) { bv = ov; bh = oh; }
      }
      if (ch == bh) cv = -1.f;
      if (lane == 0) { selv[it] = bv; seli[it] = bh; }
      ssum += bv * 0.f;  // keep shape; ssum accumulated below by lane0
      if (lane == 0) ssum_s = (it == 0) ? bv : ssum_s + bv;
    }
  }
  __syncthreads();

  const float denom = 1.f / (ssum_s + 1e-8f);
  float p[8];
  int idx[8];
#pragma unroll
  for (int k = 0; k < 8; ++k) {
    p[k] = selv[k] * denom;
    idx[k] = seli[k];
  }

  // sparse cls1: 4 consecutive outputs per thread
  const int o0 = tid * 4;
  bf16x4 o;
#pragma unroll
  for (int j = 0; j < 4; ++j) {
    const int oo = o0 + j;
    float acc = b1[oo];
#pragma unroll
    for (int k = 0; k < 8; ++k) acc += p[k] * w1[(long)oo * 1024 + idx[k]];
    o[j] = (__bf16)gelu_exact(acc);
  }
  *(bf16x4*)(hid + b * 1024 + o0) = o;
}

extern "C" void kernel_launch(void* const* d_in, const int* in_sizes, int n_in,
                              void* d_out, int out_size, void* d_ws, size_t ws_size,
                              hipStream_t stream) {
  const float* x      = (const float*)d_in[0];
  const float* proj_w = (const float*)d_in[1];
  const float* proj_b = (const float*)d_in[2];
  const float* ln_p_g = (const float*)d_in[3];
  const float* ln_p_b = (const float*)d_in[4];
  const float* wf_w   = (const float*)d_in[5];
  const float* wf_b   = (const float*)d_in[6];
  const float* ln_g   = (const float*)d_in[7];
  const float* ln_b   = (const float*)d_in[8];
  const float* temperature = (const float*)d_in[9];
  const float* phases = (const float*)d_in[10];
  const float* gate_w = (const float*)d_in[11];
  const float* gate_b = (const float*)d_in[12];
  const float* cls_w1 = (const float*)d_in[13];
  const float* cls_b1 = (const float*)d_in[14];
  const float* cls_w2 = (const float*)d_in[15];
  const float* cls_b2 = (const float*)d_in[16];
  float* out = (float*)d_out;
  (void)in_sizes; (void)n_in; (void)out_size; (void)ws_size;

  // 128MB lifetime-aliased layout:
  //   [0,32):   xb (casts,G1)            -> supr (stage_c..end)
  //   [32,64):  y1 (G1,ln) -> outc 24MB -> magb -> hid
  //   [64,96):  w1b 4MB (casts,G1)       -> supi (stage_c..end)
  //   [96,108): wfwb   [108,124): hb   [124,126): gwb   [126,128): c2b
  char* ws = (char*)d_ws;
  const size_t MB = 1024 * 1024;
  __bf16* xb    = (__bf16*)(ws + 0);
  float*  supr  = (float*)(ws + 0);
  float*  y1    = (float*)(ws + 32 * MB);
  __bf16* outc  = (__bf16*)(ws + 32 * MB);
  __bf16* magb  = (__bf16*)(ws + 32 * MB);
  __bf16* hid   = (__bf16*)(ws + 32 * MB);
  __bf16* w1b   = (__bf16*)(ws + 64 * MB);
  float*  supi  = (float*)(ws + 64 * MB);
  __bf16* wfwb  = (__bf16*)(ws + 96 * MB);
  __bf16* hb    = (__bf16*)(ws + 108 * MB);
  __bf16* gwb   = (__bf16*)(ws + 124 * MB);
  __bf16* c2b   = (__bf16*)(ws + 126 * MB);

  // casts
  k_cast_bf16<<<16384, 256, 0, stream>>>(x, xb);
  k_cast_bf16<<<2048, 256, 0, stream>>>(proj_w, w1b);
  k_cast_bf16<<<6144, 256, 0, stream>>>(wf_w, wfwb);
  k_cast_bf16<<<1024, 256, 0, stream>>>(gate_w, gwb);
  k_cast_pad<<<1024, 256, 0, stream>>>(cls_w2, c2b, 1000, 1024);

  // G1: y1 = x @ proj_w^T + proj_b  (f32)
  k_gemm_bt<0><<<dim3(8, 64), 256, 0, stream>>>(xb, w1b, proj_b, y1, 8192, 1024, 2048, 1024, nullptr, nullptr);
  // h = gelu(LN(y1))
  k_ln_gelu<<<8192, 256, 0, stream>>>(y1, ln_p_g, ln_p_b, hb);

  // G2 + stage C, chunked over batch (4 x 2048 rows)
  for (int c = 0; c < 4; ++c) {
    k_gemm_bt<1><<<dim3(48, 16), 256, 0, stream>>>(hb + (size_t)c * 2048 * 1024, wfwb, wf_b,
                                                   outc, 2048, 6144, 1024, 6144, nullptr, nullptr);
    k_stage_c<<<2048, 256, 0, stream>>>(outc, ln_g, ln_b, phases, temperature,
                                        supr, supi, c * 2048);
  }

  // self-mod x2 (gate GEMM with fused in-place update)
  for (int it = 0; it < 2; ++it) {
    k_mag<<<8192, 256, 0, stream>>>(supr, supi, magb);
    k_gemm_bt<4><<<dim3(8, 64), 256, 0, stream>>>(magb, gwb, gate_b, nullptr, 8192, 1024, 1024, 1024, supr, supi);
  }

  // fused top-8 + sparse cls1 -> hid (bf16)
  k_topk_cls1<<<8192, 256, 0, stream>>>(supr, supi, cls_w1, cls_b1, hid);
  // G5: logits = hid @ cls_w2^T + cls_b2 (f32, Nreal=1000)
  k_gemm_bt<0><<<dim3(8, 64), 256, 0, stream>>>(hid, c2b, cls_b2, out, 8192, 1024, 1024, 1000, nullptr, nullptr);
}

// Round 5
// 626.318 us; speedup vs baseline: 1.3229x; 1.3229x over previous
//
#include <hip/hip_runtime.h>
#include <cstdint>

typedef __attribute__((ext_vector_type(8))) __bf16 bf16x8;
typedef __attribute__((ext_vector_type(4))) __bf16 bf16x4;
typedef __attribute__((ext_vector_type(4))) float f32x4;

__device__ __forceinline__ void gld_lds16(const void* g, void* l) {
  __builtin_amdgcn_global_load_lds(
      (const __attribute__((address_space(1))) void*)g,
      (__attribute__((address_space(3))) void*)l, 16, 0, 0);
}

__device__ __forceinline__ float block_sum(float v, float* scr) {
#pragma unroll
  for (int off = 32; off > 0; off >>= 1) v += __shfl_down(v, off, 64);
  const int w = threadIdx.x >> 6;
  __syncthreads();
  if ((threadIdx.x & 63) == 0) scr[w] = v;
  __syncthreads();
  float s = 0.f;
  const int nw = blockDim.x >> 6;
  for (int i = 0; i < nw; ++i) s += scr[i];
  return s;
}

__device__ __forceinline__ float gelu_exact(float x) {
  return 0.5f * x * (1.f + erff(x * 0.70710678118654752f));
}

// ---------------- casts ----------------
__global__ __launch_bounds__(256) void k_cast_bf16(const float* __restrict__ in,
                                                   __bf16* __restrict__ out) {
  const long i = ((long)blockIdx.x * 256 + threadIdx.x) * 4;
  f32x4 v = *(const f32x4*)(in + i);
  bf16x4 o = {(__bf16)v[0], (__bf16)v[1], (__bf16)v[2], (__bf16)v[3]};
  *(bf16x4*)(out + i) = o;
}

__global__ __launch_bounds__(256) void k_cast_pad(const float* __restrict__ in,
                                                  __bf16* __restrict__ out,
                                                  int rows_real, int cols) {
  const long i = ((long)blockIdx.x * 256 + threadIdx.x) * 4;
  const int row = (int)(i / cols);
  const int col = (int)(i % cols);
  bf16x4 o;
  if (row < rows_real) {
    f32x4 v = *(const f32x4*)(in + (long)row * cols + col);
    o = (bf16x4){(__bf16)v[0], (__bf16)v[1], (__bf16)v[2], (__bf16)v[3]};
  } else {
    o = (bf16x4){(__bf16)0.f, (__bf16)0.f, (__bf16)0.f, (__bf16)0.f};
  }
  *(bf16x4*)(out + i) = o;
}

// ---------------- transpose 1024x1024 f32 ----------------
__global__ __launch_bounds__(256) void k_transpose1k(const float* __restrict__ in,
                                                     float* __restrict__ out) {
  __shared__ float t[32][33];
  const int tx = threadIdx.x & 31;
  const int ty = threadIdx.x >> 5;  // 0..7
  const int r0 = blockIdx.y * 32, c0 = blockIdx.x * 32;
#pragma unroll
  for (int k = 0; k < 4; ++k)
    t[ty + 8 * k][tx] = in[(long)(r0 + ty + 8 * k) * 1024 + c0 + tx];
  __syncthreads();
#pragma unroll
  for (int k = 0; k < 4; ++k)
    out[(long)(c0 + ty + 8 * k) * 1024 + r0 + tx] = t[tx][ty + 8 * k];
}

// ---------------- GEMM: C = A @ B^T + bias ----------------
// EPI: 0 = f32 store, 1 = bf16 store, 4 = fused self-mod update
template <int EPI>
__global__ __launch_bounds__(256) void k_gemm_bt(
    const __bf16* __restrict__ A, const __bf16* __restrict__ B,
    const float* __restrict__ bias, void* __restrict__ Cout,
    int M, int N, int K, int Nreal,
    float* __restrict__ supR, float* __restrict__ supI) {
  __shared__ __align__(16) __bf16 As[2][128 * 32];
  __shared__ __align__(16) __bf16 Bs[2][128 * 32];
  const int tid = threadIdx.x;
  const int lane = tid & 63;
  const int wid = tid >> 6;
  const int wr = wid >> 1, wc = wid & 1;      // 2x2 wave grid, 64x64 each

  const int gx = gridDim.x, gy = gridDim.y;
  const int nwg = gx * gy;
  int bx, by;
  if ((nwg & 7) == 0) {
    const int lin = blockIdx.y * gx + blockIdx.x;
    const int cpx = nwg >> 3;
    const int w = (lin & 7) * cpx + (lin >> 3);
    bx = w / gy;
    by = w % gy;
  } else {
    bx = blockIdx.x;
    by = blockIdx.y;
  }
  const int m0 = by * 128;
  const int n0 = bx * 128;
  const int frow = lane & 15;
  const int fk = (lane >> 4) * 8;
  f32x4 acc[4][4] = {};

  auto stage = [&](int buf, int k0) {
    const __bf16* Ab = A + (long)m0 * K + k0;
    const __bf16* Bb = B + (long)n0 * K + k0;
#pragma unroll
    for (int q = 0; q < 2; ++q) {
      const int idx = q * 256 + tid;
      const int row = idx >> 2;
      const int col = (idx & 3) * 8;
      gld_lds16(Ab + (long)row * K + col, (char*)(&As[buf][0]) + idx * 16);
      gld_lds16(Bb + (long)row * K + col, (char*)(&Bs[buf][0]) + idx * 16);
    }
  };

  const int nt = K >> 5;  // K/32 tiles
  int cur = 0;
  stage(0, 0);
  __syncthreads();
  for (int t = 0; t < nt; ++t) {
    if (t + 1 < nt) stage(cur ^ 1, (t + 1) << 5);
    bf16x8 af[4], bfr[4];
#pragma unroll
    for (int i = 0; i < 4; ++i) {
      af[i] = *(const bf16x8*)(&As[cur][0] + (wr * 64 + i * 16 + frow) * 32 + fk);
      bfr[i] = *(const bf16x8*)(&Bs[cur][0] + (wc * 64 + i * 16 + frow) * 32 + fk);
    }
#pragma unroll
    for (int im = 0; im < 4; ++im)
#pragma unroll
      for (int in = 0; in < 4; ++in)
        acc[im][in] = __builtin_amdgcn_mfma_f32_16x16x32_bf16(af[im], bfr[in],
                                                              acc[im][in], 0, 0, 0);
    __syncthreads();
    cur ^= 1;
  }

  const int crow0 = m0 + wr * 64 + (lane >> 4) * 4;
  const int ccol0 = n0 + wc * 64 + (lane & 15);
#pragma unroll
  for (int in = 0; in < 4; ++in) {
    const int col = ccol0 + in * 16;
    if (col >= Nreal) continue;
    const float bv = bias[col];
#pragma unroll
    for (int im = 0; im < 4; ++im) {
#pragma unroll
      for (int r = 0; r < 4; ++r) {
        const long row = crow0 + im * 16 + r;
        const float v = acc[im][in][r] + bv;
        if (EPI == 0) {
          ((float*)Cout)[row * Nreal + col] = v;
        } else if (EPI == 1) {
          ((__bf16*)Cout)[row * Nreal + col] = (__bf16)v;
        } else {
          const float gmul = 1.f / (1.f + expf(-v)) + 0.1f;
          const long ix = row * Nreal + col;
          supR[ix] *= gmul;
          supI[ix] *= gmul;
        }
      }
    }
  }
}

// ---------------- LN (over 1024) + exact gelu -> bf16 ----------------
__global__ __launch_bounds__(256) void k_ln_gelu(const float* __restrict__ y,
                                                 const float* __restrict__ g,
                                                 const float* __restrict__ b,
                                                 __bf16* __restrict__ h) {
  __shared__ float scr[8];
  const int tid = threadIdx.x;
  const long row = blockIdx.x;
  const float* yr = y + row * 1024;
  f32x4 v = *(const f32x4*)(yr + tid * 4);
  float ls = v[0] + v[1] + v[2] + v[3];
  const float mu = block_sum(ls, scr) * (1.f / 1024.f);
  float lss = 0.f;
#pragma unroll
  for (int j = 0; j < 4; ++j) {
    const float d = v[j] - mu;
    lss += d * d;
  }
  const float var = block_sum(lss, scr) * (1.f / 1024.f);
  const float rstd = rsqrtf(var + 1e-5f);
  bf16x4 o;
#pragma unroll
  for (int j = 0; j < 4; ++j) {
    const int c = tid * 4 + j;
    const float t = (v[j] - mu) * rstd * g[c] + b[c];
    o[j] = (__bf16)gelu_exact(t);
  }
  *(bf16x4*)(h + row * 1024 + tid * 4) = o;
}

// ---------------- stage C ----------------
__global__ __launch_bounds__(256) void k_stage_c(
    const __bf16* __restrict__ outb, const float* __restrict__ ln_g,
    const float* __restrict__ ln_b, const float* __restrict__ phases,
    const float* __restrict__ temp, float* __restrict__ supr,
    float* __restrict__ supi, int b0) {
  __shared__ float wrs[3][1024];
  __shared__ float wis[3][1024];
  __shared__ float gbuf[2048];
  __shared__ float scr[8];
  const int tid = threadIdx.x;
  const long b = blockIdx.x;

#pragma unroll 1
  for (int s = 0; s < 3; ++s) {
    const __bf16* src = outb + b * 6144 + s * 2048;
    bf16x8 v8 = *(const bf16x8*)(src + tid * 8);
    float x[8];
#pragma unroll
    for (int j = 0; j < 8; ++j) x[j] = (float)v8[j];
    float ls = 0.f;
#pragma unroll
    for (int j = 0; j < 8; ++j) ls += x[j];
    const float mu = block_sum(ls, scr) * (1.f / 2048.f);
    float lss = 0.f;
#pragma unroll
    for (int j = 0; j < 8; ++j) {
      const float d = x[j] - mu;
      lss += d * d;
    }
    const float var = block_sum(lss, scr) * (1.f / 2048.f);
    const float rstd = rsqrtf(var + 1e-5f);
    const float* lg = ln_g + s * 2048;
    const float* lb = ln_b + s * 2048;
    float nsq = 0.f;
#pragma unroll
    for (int j = 0; j < 8; ++j) {
      const int e = tid * 8 + j;
      const float yv = (x[j] - mu) * rstd * lg[e] + lb[e];
      const float gv = expf(-yv * yv);
      gbuf[e] = gv;
      nsq += gv * gv;
    }
    const float normsq = block_sum(nsq, scr) + 1e-8f; // syncs make gbuf visible
    const float factor = sqrtf(2.25f / normsq);
    const float ph = phases[s];
    const float cs = cosf(ph), sn = sinf(ph);
#pragma unroll
    for (int j = 0; j < 4; ++j) {
      const int h = j * 256 + tid;
      const float a = gbuf[h] * factor;
      const float bb = gbuf[h + 1024] * factor;
      wrs[s][h] = a * cs - bb * sn;
      wis[s][h] = a * sn + bb * cs;
    }
    __syncthreads();
  }

  float mr[4];
  float pmn = 0.f;
#pragma unroll
  for (int j = 0; j < 4; ++j) {
    const int h = j * 256 + tid;
    const float m = (wrs[0][h] + wrs[1][h] + wrs[2][h]) * (1.f / 3.f);
    mr[j] = m;
    pmn += m * m;
  }
  const float mnorm = sqrtf(block_sum(pmn, scr)) + 1e-8f;
  float csim[3];
#pragma unroll 1
  for (int s = 0; s < 3; ++s) {
    float pd = 0.f, pw = 0.f;
#pragma unroll
    for (int j = 0; j < 4; ++j) {
      const int h = j * 256 + tid;
      const float w = wrs[s][h];
      pd += w * mr[j];
      pw += w * w;
    }
    const float dot = block_sum(pd, scr);
    const float wn = sqrtf(block_sum(pw, scr)) + 1e-8f;
    csim[s] = dot / (wn * mnorm);
  }
  const float T = temp[0];
  const float t0 = csim[0] / T, t1 = csim[1] / T, t2 = csim[2] / T;
  const float mx = fmaxf(t0, fmaxf(t1, t2));
  const float e0 = expf(t0 - mx), e1 = expf(t1 - mx), e2 = expf(t2 - mx);
  const float inv = 1.f / (e0 + e1 + e2);
  const float w0 = e0 * inv, w1 = e1 * inv, w2 = e2 * inv;
#pragma unroll
  for (int j = 0; j < 4; ++j) {
    const int h = j * 256 + tid;
    supr[(long)(b0 + b) * 1024 + h] = wrs[0][h] * w0 + wrs[1][h] * w1 + wrs[2][h] * w2;
    supi[(long)(b0 + b) * 1024 + h] = wis[0][h] * w0 + wis[1][h] * w1 + wis[2][h] * w2;
  }
}

// ---------------- mag ----------------
__global__ __launch_bounds__(256) void k_mag(const float* __restrict__ sr,
                                             const float* __restrict__ si,
                                             __bf16* __restrict__ mag) {
  const long i = ((long)blockIdx.x * 256 + threadIdx.x) * 4;
  f32x4 r = *(const f32x4*)(sr + i);
  f32x4 im = *(const f32x4*)(si + i);
  bf16x4 o;
#pragma unroll
  for (int j = 0; j < 4; ++j)
    o[j] = (__bf16)sqrtf(r[j] * r[j] + im[j] * im[j] + 1e-8f);
  *(bf16x4*)(mag + i) = o;
}

// ---------------- fused top-8 + sparse cls_w1 (row-gather from w1^T) ----------------
__global__ __launch_bounds__(256) void k_topk_cls1(
    const float* __restrict__ supr, const float* __restrict__ supi,
    const float* __restrict__ w1t, const float* __restrict__ b1,
    __bf16* __restrict__ hid) {
  __shared__ float candv[32];
  __shared__ int candi[32];
  __shared__ float selv[8];
  __shared__ int seli[8];
  __shared__ float ssum_s;
  const int tid = threadIdx.x;
  const int lane = tid & 63;
  const int wv = tid >> 6;
  const long b = blockIdx.x;

  f32x4 r = *(const f32x4*)(supr + b * 1024 + tid * 4);
  f32x4 im = *(const f32x4*)(supi + b * 1024 + tid * 4);
  float myv[4];
#pragma unroll
  for (int j = 0; j < 4; ++j) myv[j] = r[j] * r[j] + im[j] * im[j];

  // stage 1: per-wave top-8 (no barriers)
  float wcv[8];
  int wch[8];
#pragma unroll 1
  for (int it = 0; it < 8; ++it) {
    float bv = -1.f;
    int bh = 1 << 30;
#pragma unroll
    for (int j = 0; j < 4; ++j)
      if (myv[j] > bv) { bv = myv[j]; bh = tid * 4 + j; }
#pragma unroll
    for (int m = 1; m < 64; m <<= 1) {
      const float ov = __shfl_xor(bv, m, 64);
      const int oh = __shfl_xor(bh, m, 64);
      if (ov > bv || (ov == bv && oh < bh)) { bv = ov; bh = oh; }
    }
    wcv[it] = bv;
    wch[it] = bh;
    const int jj = bh - tid * 4;
    if (jj >= 0 && jj < 4) myv[jj] = -1.f;
  }
  if (lane < 8) {
    candv[wv * 8 + lane] = wcv[lane];
    candi[wv * 8 + lane] = wch[lane];
  }
  __syncthreads();

  // stage 2: wave 0 merges 32 candidates -> top-8
  if (wv == 0) {
    float cv = (lane < 32) ? candv[lane] : -1.f;
    int ch = (lane < 32) ? candi[lane] : (1 << 30);
#pragma unroll 1
    for (int it = 0; it < 8; ++it) {
      float bv = cv;
      int bh = ch;
#pragma unroll
      for (int m = 1; m < 64; m <<= 1) {
        const float ov = __shfl_xor(bv, m, 64);
        const int oh = __shfl_xor(bh, m, 64);
        if (ov > bv || (ov == bv && oh < bh)) { bv = ov; bh = oh; }
      }
      if (ch == bh) cv = -1.f;
      if (lane == 0) {
        selv[it] = bv;
        seli[it] = bh;
        ssum_s = (it == 0) ? bv : ssum_s + bv;
      }
    }
  }
  __syncthreads();

  const float denom = 1.f / (ssum_s + 1e-8f);
  float p[8];
  int idx[8];
#pragma unroll
  for (int k = 0; k < 8; ++k) {
    p[k] = selv[k] * denom;
    idx[k] = seli[k];
  }

  // sparse cls1 via w1^T row gather: coalesced float4 per selected index
  const int o0 = tid * 4;
  float acc0 = b1[o0], acc1 = b1[o0 + 1], acc2 = b1[o0 + 2], acc3 = b1[o0 + 3];
#pragma unroll
  for (int k = 0; k < 8; ++k) {
    const f32x4 wrow = *(const f32x4*)(w1t + (long)idx[k] * 1024 + o0);
    acc0 += p[k] * wrow[0];
    acc1 += p[k] * wrow[1];
    acc2 += p[k] * wrow[2];
    acc3 += p[k] * wrow[3];
  }
  bf16x4 o = {(__bf16)gelu_exact(acc0), (__bf16)gelu_exact(acc1),
              (__bf16)gelu_exact(acc2), (__bf16)gelu_exact(acc3)};
  *(bf16x4*)(hid + b * 1024 + o0) = o;
}

extern "C" void kernel_launch(void* const* d_in, const int* in_sizes, int n_in,
                              void* d_out, int out_size, void* d_ws, size_t ws_size,
                              hipStream_t stream) {
  const float* x      = (const float*)d_in[0];
  const float* proj_w = (const float*)d_in[1];
  const float* proj_b = (const float*)d_in[2];
  const float* ln_p_g = (const float*)d_in[3];
  const float* ln_p_b = (const float*)d_in[4];
  const float* wf_w   = (const float*)d_in[5];
  const float* wf_b   = (const float*)d_in[6];
  const float* ln_g   = (const float*)d_in[7];
  const float* ln_b   = (const float*)d_in[8];
  const float* temperature = (const float*)d_in[9];
  const float* phases = (const float*)d_in[10];
  const float* gate_w = (const float*)d_in[11];
  const float* gate_b = (const float*)d_in[12];
  const float* cls_w1 = (const float*)d_in[13];
  const float* cls_b1 = (const float*)d_in[14];
  const float* cls_w2 = (const float*)d_in[15];
  const float* cls_b2 = (const float*)d_in[16];
  float* out = (float*)d_out;
  (void)in_sizes; (void)n_in; (void)out_size; (void)ws_size;

  // 128MB lifetime-aliased layout:
  //   [0,32):   xb (casts,G1)            -> supr (stage_c..end)
  //   [32,64):  y1 (G1,ln) -> outc 24MB -> magb -> hid
  //   [64,96):  w1b 4MB (casts,G1)       -> supi (stage_c..end)
  //   [96,108): wfwb   [108,124): hb (G1..G2) -> w1t 4MB (after G2 loop)
  //   [124,126): gwb   [126,128): c2b
  char* ws = (char*)d_ws;
  const size_t MB = 1024 * 1024;
  __bf16* xb    = (__bf16*)(ws + 0);
  float*  supr  = (float*)(ws + 0);
  float*  y1    = (float*)(ws + 32 * MB);
  __bf16* outc  = (__bf16*)(ws + 32 * MB);
  __bf16* magb  = (__bf16*)(ws + 32 * MB);
  __bf16* hid   = (__bf16*)(ws + 32 * MB);
  __bf16* w1b   = (__bf16*)(ws + 64 * MB);
  float*  supi  = (float*)(ws + 64 * MB);
  __bf16* wfwb  = (__bf16*)(ws + 96 * MB);
  __bf16* hb    = (__bf16*)(ws + 108 * MB);
  float*  w1t   = (float*)(ws + 108 * MB);  // reuses hb after G2 loop
  __bf16* gwb   = (__bf16*)(ws + 124 * MB);
  __bf16* c2b   = (__bf16*)(ws + 126 * MB);

  // casts
  k_cast_bf16<<<16384, 256, 0, stream>>>(x, xb);
  k_cast_bf16<<<2048, 256, 0, stream>>>(proj_w, w1b);
  k_cast_bf16<<<6144, 256, 0, stream>>>(wf_w, wfwb);
  k_cast_bf16<<<1024, 256, 0, stream>>>(gate_w, gwb);
  k_cast_pad<<<1024, 256, 0, stream>>>(cls_w2, c2b, 1000, 1024);

  // G1: y1 = x @ proj_w^T + proj_b  (f32)
  k_gemm_bt<0><<<dim3(8, 64), 256, 0, stream>>>(xb, w1b, proj_b, y1, 8192, 1024, 2048, 1024, nullptr, nullptr);
  // h = gelu(LN(y1))
  k_ln_gelu<<<8192, 256, 0, stream>>>(y1, ln_p_g, ln_p_b, hb);

  // G2 + stage C, chunked over batch (4 x 2048 rows)
  for (int c = 0; c < 4; ++c) {
    k_gemm_bt<1><<<dim3(48, 16), 256, 0, stream>>>(hb + (size_t)c * 2048 * 1024, wfwb, wf_b,
                                                   outc, 2048, 6144, 1024, 6144, nullptr, nullptr);
    k_stage_c<<<2048, 256, 0, stream>>>(outc, ln_g, ln_b, phases, temperature,
                                        supr, supi, c * 2048);
  }

  // hb is dead now: transpose cls_w1 into w1t for coalesced sparse gather
  k_transpose1k<<<dim3(32, 32), 256, 0, stream>>>(cls_w1, w1t);

  // self-mod x2 (gate GEMM with fused in-place update)
  for (int it = 0; it < 2; ++it) {
    k_mag<<<8192, 256, 0, stream>>>(supr, supi, magb);
    k_gemm_bt<4><<<dim3(8, 64), 256, 0, stream>>>(magb, gwb, gate_b, nullptr, 8192, 1024, 1024, 1024, supr, supi);
  }

  // fused top-8 + sparse cls1 -> hid (bf16)
  k_topk_cls1<<<8192, 256, 0, stream>>>(supr, supi, w1t, cls_b1, hid);
  // G5: logits = hid @ cls_w2^T + cls_b2 (f32, Nreal=1000)
  k_gemm_bt<0><<<dim3(8, 64), 256, 0, stream>>>(hid, c2b, cls_b2, out, 8192, 1024, 1024, 1000, nullptr, nullptr);
}

// Round 6
// 592.276 us; speedup vs baseline: 1.3989x; 1.0575x over previous
//
#include <hip/hip_runtime.h>
#include <cstdint>

typedef __attribute__((ext_vector_type(8))) __bf16 bf16x8;
typedef __attribute__((ext_vector_type(4))) __bf16 bf16x4;
typedef __attribute__((ext_vector_type(4))) float f32x4;
typedef unsigned long long u64;

__device__ __forceinline__ void gld_lds16(const void* g, void* l) {
  __builtin_amdgcn_global_load_lds(
      (const __attribute__((address_space(1))) void*)g,
      (__attribute__((address_space(3))) void*)l, 16, 0, 0);
}

__device__ __forceinline__ float block_sum(float v, float* scr) {
#pragma unroll
  for (int off = 32; off > 0; off >>= 1) v += __shfl_down(v, off, 64);
  const int w = threadIdx.x >> 6;
  __syncthreads();
  if ((threadIdx.x & 63) == 0) scr[w] = v;
  __syncthreads();
  float s = 0.f;
  const int nw = blockDim.x >> 6;
  for (int i = 0; i < nw; ++i) s += scr[i];
  return s;
}

// fast gelu: A&S 7.1.26 erf (|err|<1.5e-7) + hw exp
__device__ __forceinline__ float gelu_fast(float x) {
  const float ax = fabsf(x) * 0.70710678118654752f;
  const float t = 1.f / (1.f + 0.3275911f * ax);
  const float e = __expf(-ax * ax);
  float poly = 1.061405429f;
  poly = poly * t - 1.453152027f;
  poly = poly * t + 1.421413741f;
  poly = poly * t - 0.284496736f;
  poly = poly * t + 0.254829592f;
  const float erfax = 1.f - poly * t * e;
  const float er = copysignf(erfax, x);
  return 0.5f * x * (1.f + er);
}

// ---------------- casts ----------------
__global__ __launch_bounds__(256) void k_cast_bf16(const float* __restrict__ in,
                                                   __bf16* __restrict__ out) {
  const long i = ((long)blockIdx.x * 256 + threadIdx.x) * 4;
  f32x4 v = *(const f32x4*)(in + i);
  bf16x4 o = {(__bf16)v[0], (__bf16)v[1], (__bf16)v[2], (__bf16)v[3]};
  *(bf16x4*)(out + i) = o;
}

__global__ __launch_bounds__(256) void k_cast_pad(const float* __restrict__ in,
                                                  __bf16* __restrict__ out,
                                                  int rows_real, int cols) {
  const long i = ((long)blockIdx.x * 256 + threadIdx.x) * 4;
  const int row = (int)(i / cols);
  const int col = (int)(i % cols);
  bf16x4 o;
  if (row < rows_real) {
    f32x4 v = *(const f32x4*)(in + (long)row * cols + col);
    o = (bf16x4){(__bf16)v[0], (__bf16)v[1], (__bf16)v[2], (__bf16)v[3]};
  } else {
    o = (bf16x4){(__bf16)0.f, (__bf16)0.f, (__bf16)0.f, (__bf16)0.f};
  }
  *(bf16x4*)(out + i) = o;
}

// ---------------- transpose 1024x1024 f32 ----------------
__global__ __launch_bounds__(256) void k_transpose1k(const float* __restrict__ in,
                                                     float* __restrict__ out) {
  __shared__ float t[32][33];
  const int tx = threadIdx.x & 31;
  const int ty = threadIdx.x >> 5;
  const int r0 = blockIdx.y * 32, c0 = blockIdx.x * 32;
#pragma unroll
  for (int k = 0; k < 4; ++k)
    t[ty + 8 * k][tx] = in[(long)(r0 + ty + 8 * k) * 1024 + c0 + tx];
  __syncthreads();
#pragma unroll
  for (int k = 0; k < 4; ++k)
    out[(long)(c0 + ty + 8 * k) * 1024 + r0 + tx] = t[tx][ty + 8 * k];
}

// ---------------- GEMM: C = A @ B^T + bias ----------------
// Tile BM x 128, BK=32, dbuf 2-phase. EPI: 0 f32, 1 bf16, 4 fused self-mod.
template <int EPI, int BM>
__global__ __launch_bounds__(256) void k_gemm_bt(
    const __bf16* __restrict__ A, const __bf16* __restrict__ B,
    const float* __restrict__ bias, void* __restrict__ Cout,
    int M, int N, int K, int Nreal,
    float* __restrict__ supR, float* __restrict__ supI) {
  constexpr int MR = BM / 32;  // 16-row fragments per wave (wave covers BM/2)
  __shared__ __align__(16) __bf16 As[2][BM * 32];
  __shared__ __align__(16) __bf16 Bs[2][128 * 32];
  const int tid = threadIdx.x;
  const int lane = tid & 63;
  const int wid = tid >> 6;
  const int wr = wid >> 1, wc = wid & 1;  // 2x2 wave grid

  const int gx = gridDim.x, gy = gridDim.y;
  const int nwg = gx * gy;
  int bx, by;
  if ((nwg & 7) == 0) {
    const int lin = blockIdx.y * gx + blockIdx.x;
    const int cpx = nwg >> 3;
    const int w = (lin & 7) * cpx + (lin >> 3);
    bx = w / gy;
    by = w % gy;
  } else {
    bx = blockIdx.x;
    by = blockIdx.y;
  }
  const int m0 = by * BM;
  const int n0 = bx * 128;
  const int frow = lane & 15;
  const int fk = (lane >> 4) * 8;
  f32x4 acc[MR][4] = {};

  auto stage = [&](int buf, int k0) {
    const __bf16* Ab = A + (long)m0 * K + k0;
    const __bf16* Bb = B + (long)n0 * K + k0;
#pragma unroll
    for (int q = 0; q < BM / 64; ++q) {
      const int idx = q * 256 + tid;
      const int row = idx >> 2;
      const int col = (idx & 3) * 8;
      gld_lds16(Ab + (long)row * K + col, (char*)(&As[buf][0]) + idx * 16);
    }
#pragma unroll
    for (int q = 0; q < 2; ++q) {
      const int idx = q * 256 + tid;
      const int row = idx >> 2;
      const int col = (idx & 3) * 8;
      gld_lds16(Bb + (long)row * K + col, (char*)(&Bs[buf][0]) + idx * 16);
    }
  };

  const int nt = K >> 5;
  int cur = 0;
  stage(0, 0);
  __syncthreads();
  for (int t = 0; t < nt; ++t) {
    if (t + 1 < nt) stage(cur ^ 1, (t + 1) << 5);
    bf16x8 af[MR], bfr[4];
#pragma unroll
    for (int i = 0; i < MR; ++i)
      af[i] = *(const bf16x8*)(&As[cur][0] + (wr * (BM / 2) + i * 16 + frow) * 32 + fk);
#pragma unroll
    for (int i = 0; i < 4; ++i)
      bfr[i] = *(const bf16x8*)(&Bs[cur][0] + (wc * 64 + i * 16 + frow) * 32 + fk);
#pragma unroll
    for (int im = 0; im < MR; ++im)
#pragma unroll
      for (int in = 0; in < 4; ++in)
        acc[im][in] = __builtin_amdgcn_mfma_f32_16x16x32_bf16(af[im], bfr[in],
                                                              acc[im][in], 0, 0, 0);
    __syncthreads();
    cur ^= 1;
  }

  const int crow0 = m0 + wr * (BM / 2) + (lane >> 4) * 4;
  const int ccol0 = n0 + wc * 64 + (lane & 15);
#pragma unroll
  for (int in = 0; in < 4; ++in) {
    const int col = ccol0 + in * 16;
    if (col >= Nreal) continue;
    const float bv = bias[col];
#pragma unroll
    for (int im = 0; im < MR; ++im) {
#pragma unroll
      for (int r = 0; r < 4; ++r) {
        const long row = crow0 + im * 16 + r;
        const float v = acc[im][in][r] + bv;
        if (EPI == 0) {
          ((float*)Cout)[row * Nreal + col] = v;
        } else if (EPI == 1) {
          ((__bf16*)Cout)[row * Nreal + col] = (__bf16)v;
        } else {
          const float gmul = 1.f / (1.f + __expf(-v)) + 0.1f;
          const long ix = row * Nreal + col;
          supR[ix] *= gmul;
          supI[ix] *= gmul;
        }
      }
    }
  }
}

// ---------------- LN (over 1024) + gelu -> bf16 ----------------
__global__ __launch_bounds__(256) void k_ln_gelu(const float* __restrict__ y,
                                                 const float* __restrict__ g,
                                                 const float* __restrict__ b,
                                                 __bf16* __restrict__ h) {
  __shared__ float scr[8];
  const int tid = threadIdx.x;
  const long row = blockIdx.x;
  const float* yr = y + row * 1024;
  f32x4 v = *(const f32x4*)(yr + tid * 4);
  float ls = v[0] + v[1] + v[2] + v[3];
  const float mu = block_sum(ls, scr) * (1.f / 1024.f);
  float lss = 0.f;
#pragma unroll
  for (int j = 0; j < 4; ++j) {
    const float d = v[j] - mu;
    lss += d * d;
  }
  const float var = block_sum(lss, scr) * (1.f / 1024.f);
  const float rstd = rsqrtf(var + 1e-5f);
  bf16x4 o;
#pragma unroll
  for (int j = 0; j < 4; ++j) {
    const int c = tid * 4 + j;
    const float t = (v[j] - mu) * rstd * g[c] + b[c];
    o[j] = (__bf16)gelu_fast(t);
  }
  *(bf16x4*)(h + row * 1024 + tid * 4) = o;
}

// ---------------- stage C ----------------
__global__ __launch_bounds__(256) void k_stage_c(
    const __bf16* __restrict__ outb, const float* __restrict__ ln_g,
    const float* __restrict__ ln_b, const float* __restrict__ phases,
    const float* __restrict__ temp, float* __restrict__ supr,
    float* __restrict__ supi, int b0) {
  __shared__ float wrs[3][1024];
  __shared__ float wis[3][1024];
  __shared__ float gbuf[2048];
  __shared__ float scr[8];
  const int tid = threadIdx.x;
  const long b = blockIdx.x;

#pragma unroll 1
  for (int s = 0; s < 3; ++s) {
    const __bf16* src = outb + b * 6144 + s * 2048;
    bf16x8 v8 = *(const bf16x8*)(src + tid * 8);
    float x[8];
#pragma unroll
    for (int j = 0; j < 8; ++j) x[j] = (float)v8[j];
    float ls = 0.f;
#pragma unroll
    for (int j = 0; j < 8; ++j) ls += x[j];
    const float mu = block_sum(ls, scr) * (1.f / 2048.f);
    float lss = 0.f;
#pragma unroll
    for (int j = 0; j < 8; ++j) {
      const float d = x[j] - mu;
      lss += d * d;
    }
    const float var = block_sum(lss, scr) * (1.f / 2048.f);
    const float rstd = rsqrtf(var + 1e-5f);
    const float* lg = ln_g + s * 2048;
    const float* lb = ln_b + s * 2048;
    float nsq = 0.f;
#pragma unroll
    for (int j = 0; j < 8; ++j) {
      const int e = tid * 8 + j;
      const float yv = (x[j] - mu) * rstd * lg[e] + lb[e];
      const float gv = __expf(-yv * yv);
      gbuf[e] = gv;
      nsq += gv * gv;
    }
    const float normsq = block_sum(nsq, scr) + 1e-8f;
    const float factor = sqrtf(2.25f / normsq);
    const float ph = phases[s];
    const float cs = cosf(ph), sn = sinf(ph);
#pragma unroll
    for (int j = 0; j < 4; ++j) {
      const int h = j * 256 + tid;
      const float a = gbuf[h] * factor;
      const float bb = gbuf[h + 1024] * factor;
      wrs[s][h] = a * cs - bb * sn;
      wis[s][h] = a * sn + bb * cs;
    }
    __syncthreads();
  }

  float mr[4];
  float pmn = 0.f;
#pragma unroll
  for (int j = 0; j < 4; ++j) {
    const int h = j * 256 + tid;
    const float m = (wrs[0][h] + wrs[1][h] + wrs[2][h]) * (1.f / 3.f);
    mr[j] = m;
    pmn += m * m;
  }
  const float mnorm = sqrtf(block_sum(pmn, scr)) + 1e-8f;
  float csim[3];
#pragma unroll 1
  for (int s = 0; s < 3; ++s) {
    float pd = 0.f, pw = 0.f;
#pragma unroll
    for (int j = 0; j < 4; ++j) {
      const int h = j * 256 + tid;
      const float w = wrs[s][h];
      pd += w * mr[j];
      pw += w * w;
    }
    const float dot = block_sum(pd, scr);
    const float wn = sqrtf(block_sum(pw, scr)) + 1e-8f;
    csim[s] = dot / (wn * mnorm);
  }
  const float T = temp[0];
  const float t0 = csim[0] / T, t1 = csim[1] / T, t2 = csim[2] / T;
  const float mx = fmaxf(t0, fmaxf(t1, t2));
  const float e0 = __expf(t0 - mx), e1 = __expf(t1 - mx), e2 = __expf(t2 - mx);
  const float inv = 1.f / (e0 + e1 + e2);
  const float w0 = e0 * inv, w1 = e1 * inv, w2 = e2 * inv;
#pragma unroll
  for (int j = 0; j < 4; ++j) {
    const int h = j * 256 + tid;
    supr[(long)(b0 + b) * 1024 + h] = wrs[0][h] * w0 + wrs[1][h] * w1 + wrs[2][h] * w2;
    supi[(long)(b0 + b) * 1024 + h] = wis[0][h] * w0 + wis[1][h] * w1 + wis[2][h] * w2;
  }
}

// ---------------- mag ----------------
__global__ __launch_bounds__(256) void k_mag(const float* __restrict__ sr,
                                             const float* __restrict__ si,
                                             __bf16* __restrict__ mag) {
  const long i = ((long)blockIdx.x * 256 + threadIdx.x) * 4;
  f32x4 r = *(const f32x4*)(sr + i);
  f32x4 im = *(const f32x4*)(si + i);
  bf16x4 o;
#pragma unroll
  for (int j = 0; j < 4; ++j)
    o[j] = (__bf16)sqrtf(r[j] * r[j] + im[j] * im[j] + 1e-8f);
  *(bf16x4*)(mag + i) = o;
}

// ---------------- fused top-8 (u64-key selection) + sparse cls1 ----------------
__global__ __launch_bounds__(256) void k_topk_cls1(
    const float* __restrict__ supr, const float* __restrict__ supi,
    const float* __restrict__ w1t, const float* __restrict__ b1,
    __bf16* __restrict__ hid) {
  __shared__ u64 candk[32];
  __shared__ u64 selk_s[8];
  __shared__ float ssum_s;
  const int tid = threadIdx.x;
  const int lane = tid & 63;
  const int wv = tid >> 6;
  const long b = blockIdx.x;

  f32x4 r = *(const f32x4*)(supr + b * 1024 + tid * 4);
  f32x4 im = *(const f32x4*)(supi + b * 1024 + tid * 4);
  // packed keys: (float_bits << 32) | ~idx  (value >= 0 -> monotone; tie -> lower idx)
  u64 key[4];
#pragma unroll
  for (int j = 0; j < 4; ++j) {
    const float v = r[j] * r[j] + im[j] * im[j];
    key[j] = ((u64)__float_as_uint(v) << 32) | (unsigned)(~(unsigned)(tid * 4 + j));
  }
  // running lane max
  u64 lm = key[0];
  int jm = 0;
#pragma unroll
  for (int j = 1; j < 4; ++j)
    if (key[j] > lm) { lm = key[j]; jm = j; }

  // stage 1: per-wave top-8 by iterative extraction
#pragma unroll 1
  for (int it = 0; it < 8; ++it) {
    u64 bk = lm;
#pragma unroll
    for (int m = 1; m < 64; m <<= 1) {
      const u64 ok = __shfl_xor(bk, m, 64);
      bk = ok > bk ? ok : bk;
    }
    if (lane == 0) candk[wv * 8 + it] = bk;
    if (bk == lm) {  // this lane owned the winner: remove and rescan
      key[jm] = 0ULL;
      lm = key[0]; jm = 0;
#pragma unroll
      for (int j = 1; j < 4; ++j)
        if (key[j] > lm) { lm = key[j]; jm = j; }
    }
  }
  __syncthreads();

  // stage 2: wave 0 merges 32 candidates
  if (wv == 0) {
    u64 ck = (lane < 32) ? candk[lane] : 0ULL;
    float ss = 0.f;
#pragma unroll 1
    for (int it = 0; it < 8; ++it) {
      u64 bk = ck;
#pragma unroll
      for (int m = 1; m < 64; m <<= 1) {
        const u64 ok = __shfl_xor(bk, m, 64);
        bk = ok > bk ? ok : bk;
      }
      if (ck == bk) ck = 0ULL;
      if (lane == 0) {
        selk_s[it] = bk;
        ss += __uint_as_float((unsigned)(bk >> 32));
      }
    }
    if (lane == 0) ssum_s = ss;
  }
  __syncthreads();

  const float denom = 1.f / (ssum_s + 1e-8f);
  float p[8];
  int idx[8];
#pragma unroll
  for (int k = 0; k < 8; ++k) {
    const u64 kk = selk_s[k];
    p[k] = __uint_as_float((unsigned)(kk >> 32)) * denom;
    idx[k] = (int)(~(unsigned)kk & 1023u);
  }

  // sparse cls1 via w1^T row gather (coalesced float4)
  const int o0 = tid * 4;
  float acc0 = b1[o0], acc1 = b1[o0 + 1], acc2 = b1[o0 + 2], acc3 = b1[o0 + 3];
#pragma unroll
  for (int k = 0; k < 8; ++k) {
    const f32x4 wrow = *(const f32x4*)(w1t + (long)idx[k] * 1024 + o0);
    acc0 += p[k] * wrow[0];
    acc1 += p[k] * wrow[1];
    acc2 += p[k] * wrow[2];
    acc3 += p[k] * wrow[3];
  }
  bf16x4 o = {(__bf16)gelu_fast(acc0), (__bf16)gelu_fast(acc1),
              (__bf16)gelu_fast(acc2), (__bf16)gelu_fast(acc3)};
  *(bf16x4*)(hid + b * 1024 + o0) = o;
}

extern "C" void kernel_launch(void* const* d_in, const int* in_sizes, int n_in,
                              void* d_out, int out_size, void* d_ws, size_t ws_size,
                              hipStream_t stream) {
  const float* x      = (const float*)d_in[0];
  const float* proj_w = (const float*)d_in[1];
  const float* proj_b = (const float*)d_in[2];
  const float* ln_p_g = (const float*)d_in[3];
  const float* ln_p_b = (const float*)d_in[4];
  const float* wf_w   = (const float*)d_in[5];
  const float* wf_b   = (const float*)d_in[6];
  const float* ln_g   = (const float*)d_in[7];
  const float* ln_b   = (const float*)d_in[8];
  const float* temperature = (const float*)d_in[9];
  const float* phases = (const float*)d_in[10];
  const float* gate_w = (const float*)d_in[11];
  const float* gate_b = (const float*)d_in[12];
  const float* cls_w1 = (const float*)d_in[13];
  const float* cls_b1 = (const float*)d_in[14];
  const float* cls_w2 = (const float*)d_in[15];
  const float* cls_b2 = (const float*)d_in[16];
  float* out = (float*)d_out;
  (void)in_sizes; (void)n_in; (void)out_size;

  char* ws = (char*)d_ws;
  const size_t MB = 1024 * 1024;

  if (ws_size >= 196 * MB) {
    // ---- full layout (196MB): un-chunked G2 + single stage_c ----
    //  [0,32): xb -> supr          [32,64): y1 -> supi
    //  [64,160): outb 96MB -> { magb@64, hid@80, w1t@96 }
    //  [160,176): hb   [176,188): wfwb
    //  [188,190): gwb  [190,192): c2b  [192,196): w1b
    __bf16* xb   = (__bf16*)(ws + 0);
    float*  supr = (float*)(ws + 0);
    float*  y1   = (float*)(ws + 32 * MB);
    float*  supi = (float*)(ws + 32 * MB);
    __bf16* outb = (__bf16*)(ws + 64 * MB);
    __bf16* magb = (__bf16*)(ws + 64 * MB);
    __bf16* hid  = (__bf16*)(ws + 80 * MB);
    float*  w1t  = (float*)(ws + 96 * MB);
    __bf16* hb   = (__bf16*)(ws + 160 * MB);
    __bf16* wfwb = (__bf16*)(ws + 176 * MB);
    __bf16* gwb  = (__bf16*)(ws + 188 * MB);
    __bf16* c2b  = (__bf16*)(ws + 190 * MB);
    __bf16* w1b  = (__bf16*)(ws + 192 * MB);

    k_cast_bf16<<<16384, 256, 0, stream>>>(x, xb);
    k_cast_bf16<<<2048, 256, 0, stream>>>(proj_w, w1b);
    k_cast_bf16<<<6144, 256, 0, stream>>>(wf_w, wfwb);
    k_cast_bf16<<<1024, 256, 0, stream>>>(gate_w, gwb);
    k_cast_pad<<<1024, 256, 0, stream>>>(cls_w2, c2b, 1000, 1024);

    k_gemm_bt<0, 64><<<dim3(8, 128), 256, 0, stream>>>(xb, w1b, proj_b, y1, 8192, 1024, 2048, 1024, nullptr, nullptr);
    k_ln_gelu<<<8192, 256, 0, stream>>>(y1, ln_p_g, ln_p_b, hb);

    k_gemm_bt<1, 128><<<dim3(48, 64), 256, 0, stream>>>(hb, wfwb, wf_b, outb, 8192, 6144, 1024, 6144, nullptr, nullptr);
    k_stage_c<<<8192, 256, 0, stream>>>(outb, ln_g, ln_b, phases, temperature, supr, supi, 0);

    k_transpose1k<<<dim3(32, 32), 256, 0, stream>>>(cls_w1, w1t);
    for (int it = 0; it < 2; ++it) {
      k_mag<<<8192, 256, 0, stream>>>(supr, supi, magb);
      k_gemm_bt<4, 64><<<dim3(8, 128), 256, 0, stream>>>(magb, gwb, gate_b, nullptr, 8192, 1024, 1024, 1024, supr, supi);
    }
    k_topk_cls1<<<8192, 256, 0, stream>>>(supr, supi, w1t, cls_b1, hid);
    k_gemm_bt<0, 64><<<dim3(8, 128), 256, 0, stream>>>(hid, c2b, cls_b2, out, 8192, 1024, 1024, 1000, nullptr, nullptr);
  } else {
    // ---- fallback layout (128MB): proven 4-chunk path ----
    __bf16* xb    = (__bf16*)(ws + 0);
    float*  supr  = (float*)(ws + 0);
    float*  y1    = (float*)(ws + 32 * MB);
    __bf16* outc  = (__bf16*)(ws + 32 * MB);
    __bf16* magb  = (__bf16*)(ws + 32 * MB);
    __bf16* hid   = (__bf16*)(ws + 32 * MB);
    __bf16* w1b   = (__bf16*)(ws + 64 * MB);
    float*  supi  = (float*)(ws + 64 * MB);
    __bf16* wfwb  = (__bf16*)(ws + 96 * MB);
    __bf16* hb    = (__bf16*)(ws + 108 * MB);
    float*  w1t   = (float*)(ws + 108 * MB);
    __bf16* gwb   = (__bf16*)(ws + 124 * MB);
    __bf16* c2b   = (__bf16*)(ws + 126 * MB);

    k_cast_bf16<<<16384, 256, 0, stream>>>(x, xb);
    k_cast_bf16<<<2048, 256, 0, stream>>>(proj_w, w1b);
    k_cast_bf16<<<6144, 256, 0, stream>>>(wf_w, wfwb);
    k_cast_bf16<<<1024, 256, 0, stream>>>(gate_w, gwb);
    k_cast_pad<<<1024, 256, 0, stream>>>(cls_w2, c2b, 1000, 1024);

    k_gemm_bt<0, 64><<<dim3(8, 128), 256, 0, stream>>>(xb, w1b, proj_b, y1, 8192, 1024, 2048, 1024, nullptr, nullptr);
    k_ln_gelu<<<8192, 256, 0, stream>>>(y1, ln_p_g, ln_p_b, hb);

    for (int c = 0; c < 4; ++c) {
      k_gemm_bt<1, 128><<<dim3(48, 16), 256, 0, stream>>>(hb + (size_t)c * 2048 * 1024, wfwb, wf_b,
                                                          outc, 2048, 6144, 1024, 6144, nullptr, nullptr);
      k_stage_c<<<2048, 256, 0, stream>>>(outc, ln_g, ln_b, phases, temperature,
                                          supr, supi, c * 2048);
    }

    k_transpose1k<<<dim3(32, 32), 256, 0, stream>>>(cls_w1, w1t);
    for (int it = 0; it < 2; ++it) {
      k_mag<<<8192, 256, 0, stream>>>(supr, supi, magb);
      k_gemm_bt<4, 64><<<dim3(8, 128), 256, 0, stream>>>(magb, gwb, gate_b, nullptr, 8192, 1024, 1024, 1024, supr, supi);
    }
    k_topk_cls1<<<8192, 256, 0, stream>>>(supr, supi, w1t, cls_b1, hid);
    k_gemm_bt<0, 64><<<dim3(8, 128), 256, 0, stream>>>(hid, c2b, cls_b2, out, 8192, 1024, 1024, 1000, nullptr, nullptr);
  }
}

// Round 7
// 561.265 us; speedup vs baseline: 1.4762x; 1.0553x over previous
//
#include <hip/hip_runtime.h>
#include <cstdint>

typedef __attribute__((ext_vector_type(8))) __bf16 bf16x8;
typedef __attribute__((ext_vector_type(4))) __bf16 bf16x4;
typedef __attribute__((ext_vector_type(4))) float f32x4;
typedef unsigned long long u64;

__device__ __forceinline__ void gld_lds16(const void* g, void* l) {
  __builtin_amdgcn_global_load_lds(
      (const __attribute__((address_space(1))) void*)g,
      (__attribute__((address_space(3))) void*)l, 16, 0, 0);
}

__device__ __forceinline__ float block_sum(float v, float* scr) {
#pragma unroll
  for (int off = 32; off > 0; off >>= 1) v += __shfl_down(v, off, 64);
  const int w = threadIdx.x >> 6;
  __syncthreads();
  if ((threadIdx.x & 63) == 0) scr[w] = v;
  __syncthreads();
  float s = 0.f;
  const int nw = blockDim.x >> 6;
  for (int i = 0; i < nw; ++i) s += scr[i];
  return s;
}

// fast gelu: A&S 7.1.26 erf (|err|<1.5e-7) + hw exp
__device__ __forceinline__ float gelu_fast(float x) {
  const float ax = fabsf(x) * 0.70710678118654752f;
  const float t = 1.f / (1.f + 0.3275911f * ax);
  const float e = __expf(-ax * ax);
  float poly = 1.061405429f;
  poly = poly * t - 1.453152027f;
  poly = poly * t + 1.421413741f;
  poly = poly * t - 0.284496736f;
  poly = poly * t + 0.254829592f;
  const float erfax = 1.f - poly * t * e;
  const float er = copysignf(erfax, x);
  return 0.5f * x * (1.f + er);
}

// ---------------- casts ----------------
__global__ __launch_bounds__(256) void k_cast_bf16(const float* __restrict__ in,
                                                   __bf16* __restrict__ out) {
  const long i = ((long)blockIdx.x * 256 + threadIdx.x) * 4;
  f32x4 v = *(const f32x4*)(in + i);
  bf16x4 o = {(__bf16)v[0], (__bf16)v[1], (__bf16)v[2], (__bf16)v[3]};
  *(bf16x4*)(out + i) = o;
}

__global__ __launch_bounds__(256) void k_cast_pad(const float* __restrict__ in,
                                                  __bf16* __restrict__ out,
                                                  int rows_real, int cols) {
  const long i = ((long)blockIdx.x * 256 + threadIdx.x) * 4;
  const int row = (int)(i / cols);
  const int col = (int)(i % cols);
  bf16x4 o;
  if (row < rows_real) {
    f32x4 v = *(const f32x4*)(in + (long)row * cols + col);
    o = (bf16x4){(__bf16)v[0], (__bf16)v[1], (__bf16)v[2], (__bf16)v[3]};
  } else {
    o = (bf16x4){(__bf16)0.f, (__bf16)0.f, (__bf16)0.f, (__bf16)0.f};
  }
  *(bf16x4*)(out + i) = o;
}

// ---------------- transpose 1024x1024 f32 ----------------
__global__ __launch_bounds__(256) void k_transpose1k(const float* __restrict__ in,
                                                     float* __restrict__ out) {
  __shared__ float t[32][33];
  const int tx = threadIdx.x & 31;
  const int ty = threadIdx.x >> 5;
  const int r0 = blockIdx.y * 32, c0 = blockIdx.x * 32;
#pragma unroll
  for (int k = 0; k < 4; ++k)
    t[ty + 8 * k][tx] = in[(long)(r0 + ty + 8 * k) * 1024 + c0 + tx];
  __syncthreads();
#pragma unroll
  for (int k = 0; k < 4; ++k)
    out[(long)(c0 + ty + 8 * k) * 1024 + r0 + tx] = t[tx][ty + 8 * k];
}

// ============ 256x256 8-wave BK=64 phase-interleaved GEMM (bf16 out) ============
// C = A @ B^T + bias. M%256==0, N%256==0, K%64==0, grid (N/256, M/256), 512 thr.
// Counted vmcnt pipeline (T3+T4), XOR bank-swizzle both-sides (T2),
// setprio around MFMA (T5), bijective XCD swizzle (T1).
__global__ __launch_bounds__(512, 1) void k_gemm256_bt(
    const __bf16* __restrict__ A, const __bf16* __restrict__ B,
    const float* __restrict__ bias, __bf16* __restrict__ C,
    int M, int N, int K) {
  __shared__ __align__(16) __bf16 lds[2][2][256 * 64];  // [slot][mat][row*64+k]
  const int tid = threadIdx.x;
  const int lane = tid & 63;
  const int wid = tid >> 6;
  const int wr = wid >> 2;   // 0..1 : 128-row group
  const int wc = wid & 3;    // 0..3 : 64-col group
  const int gx = gridDim.x, gy = gridDim.y;
  const int nwg = gx * gy;
  const int lin = blockIdx.y * gx + blockIdx.x;
  const int cpx = nwg >> 3;  // nwg % 8 == 0 by construction
  const int wsw = (lin & 7) * cpx + (lin >> 3);
  const int bx = wsw / gy, by = wsw % gy;
  const int m0 = by * 256, n0 = bx * 256;
  const int fr = lane & 15;  // fragment row
  const int fx = lane >> 4;  // 0..3 : k-subgroup
  const int px = lane & 7;   // read-side swizzle key (== row&7 for all frags)

  const __bf16* Abase = A + (long)m0 * K;
  const __bf16* Bbase = B + (long)n0 * K;

  // stage one quarter-tile (128 rows x 64 k) of tile kt into slot: 2 gload_lds.
  // LDS dest linear; global source pre-swizzled with the same involution
  // (blk ^= row&7) that the reads apply.
  auto stage_q = [&](int slot, int kt, int mat, int half) {
    const __bf16* src = (mat ? Bbase : Abase) + kt * 64;
#pragma unroll
    for (int q = 0; q < 2; ++q) {
      const int idx = q * 512 + tid;   // [0,1024)
      const int r = idx >> 3;          // 0..127
      const int pblk = idx & 7;        // 16B block within 128B row
      const int row = half * 128 + r;
      const int lblk = pblk ^ (r & 7); // involution
      gld_lds16(src + (long)row * K + lblk * 8,
                (char*)&lds[slot][mat][row * 64 + pblk * 8]);
    }
  };
  // read a bf16x8 fragment (row, k-slice ks) with swizzled block index
  auto frag = [&](int slot, int mat, int row, int ks) -> bf16x8 {
    return *(const bf16x8*)&lds[slot][mat][row * 64 + ((((ks << 2) + fx) ^ px) << 3)];
  };

  f32x4 acc[8][4] = {};
  const int nt = K >> 6;
  // prologue: full tile 0 -> slot 0 (8 loads outstanding)
#pragma unroll
  for (int qp = 0; qp < 4; ++qp) stage_q(0, 0, qp >> 1, qp & 1);

  const int arow = wr * 128 + fr;
  const int brow = wc * 64 + fr;

  for (int t = 0; t < nt; ++t) {
    const int sc = t & 1, sn = sc ^ 1;
    const bool pf = (t + 1 < nt);
    // ---- slot-valid wait: keep newest 2 loads (next tile q0) in flight ----
    if (pf) {
      stage_q(sn, t + 1, 0, 0);
      asm volatile("s_waitcnt vmcnt(2)" ::: "memory");
    } else {
      asm volatile("s_waitcnt vmcnt(0)" ::: "memory");
    }
    __builtin_amdgcn_sched_barrier(0);
    __builtin_amdgcn_s_barrier();
    // B fragments for both k-slices (persist across phases)
    bf16x8 b0[4], b1[4];
#pragma unroll
    for (int j = 0; j < 4; ++j) {
      b0[j] = frag(sc, 1, brow + j * 16, 0);
      b1[j] = frag(sc, 1, brow + j * 16, 1);
    }
#define DO_PHASE(P, STG)                                                       \
  {                                                                            \
    STG;                                                                       \
    bf16x8 a00 = frag(sc, 0, arow + (2 * (P)) * 16, 0);                        \
    bf16x8 a01 = frag(sc, 0, arow + (2 * (P)) * 16, 1);                        \
    bf16x8 a10 = frag(sc, 0, arow + (2 * (P) + 1) * 16, 0);                    \
    bf16x8 a11 = frag(sc, 0, arow + (2 * (P) + 1) * 16, 1);                    \
    __builtin_amdgcn_s_barrier();                                              \
    __builtin_amdgcn_s_setprio(1);                                             \
    _Pragma("unroll") for (int j = 0; j < 4; ++j) {                            \
      acc[2 * (P)][j] = __builtin_amdgcn_mfma_f32_16x16x32_bf16(               \
          a00, b0[j], acc[2 * (P)][j], 0, 0, 0);                               \
      acc[2 * (P)][j] = __builtin_amdgcn_mfma_f32_16x16x32_bf16(               \
          a01, b1[j], acc[2 * (P)][j], 0, 0, 0);                               \
      acc[2 * (P) + 1][j] = __builtin_amdgcn_mfma_f32_16x16x32_bf16(           \
          a10, b0[j], acc[2 * (P) + 1][j], 0, 0, 0);                           \
      acc[2 * (P) + 1][j] = __builtin_amdgcn_mfma_f32_16x16x32_bf16(           \
          a11, b1[j], acc[2 * (P) + 1][j], 0, 0, 0);                           \
    }                                                                          \
    __builtin_amdgcn_s_setprio(0);                                             \
    __builtin_amdgcn_s_barrier();                                              \
  }
    DO_PHASE(0, )
    DO_PHASE(1, if (pf) stage_q(sn, t + 1, 0, 1))
    DO_PHASE(2, if (pf) stage_q(sn, t + 1, 1, 0))
    DO_PHASE(3, if (pf) stage_q(sn, t + 1, 1, 1))
#undef DO_PHASE
  }

  const int crow0 = m0 + wr * 128 + fx * 4;
  const int ccol0 = n0 + wc * 64 + fr;
#pragma unroll
  for (int j = 0; j < 4; ++j) {
    const int col = ccol0 + j * 16;
    const float bv = bias[col];
#pragma unroll
    for (int im = 0; im < 8; ++im)
#pragma unroll
      for (int r = 0; r < 4; ++r)
        C[(long)(crow0 + im * 16 + r) * N + col] = (__bf16)(acc[im][j][r] + bv);
  }
}

// ---------------- GEMM: C = A @ B^T + bias (128-col tiles) ----------------
// EPI: 0 f32, 1 bf16, 4 fused self-mod update
template <int EPI, int BM>
__global__ __launch_bounds__(256) void k_gemm_bt(
    const __bf16* __restrict__ A, const __bf16* __restrict__ B,
    const float* __restrict__ bias, void* __restrict__ Cout,
    int M, int N, int K, int Nreal,
    float* __restrict__ supR, float* __restrict__ supI) {
  constexpr int MR = BM / 32;
  __shared__ __align__(16) __bf16 As[2][BM * 32];
  __shared__ __align__(16) __bf16 Bs[2][128 * 32];
  const int tid = threadIdx.x;
  const int lane = tid & 63;
  const int wid = tid >> 6;
  const int wr = wid >> 1, wc = wid & 1;

  const int gx = gridDim.x, gy = gridDim.y;
  const int nwg = gx * gy;
  int bx, by;
  if ((nwg & 7) == 0) {
    const int lin = blockIdx.y * gx + blockIdx.x;
    const int cpx = nwg >> 3;
    const int w = (lin & 7) * cpx + (lin >> 3);
    bx = w / gy;
    by = w % gy;
  } else {
    bx = blockIdx.x;
    by = blockIdx.y;
  }
  const int m0 = by * BM;
  const int n0 = bx * 128;
  const int frow = lane & 15;
  const int fk = (lane >> 4) * 8;
  f32x4 acc[MR][4] = {};

  auto stage = [&](int buf, int k0) {
    const __bf16* Ab = A + (long)m0 * K + k0;
    const __bf16* Bb = B + (long)n0 * K + k0;
#pragma unroll
    for (int q = 0; q < BM / 64; ++q) {
      const int idx = q * 256 + tid;
      const int row = idx >> 2;
      const int col = (idx & 3) * 8;
      gld_lds16(Ab + (long)row * K + col, (char*)(&As[buf][0]) + idx * 16);
    }
#pragma unroll
    for (int q = 0; q < 2; ++q) {
      const int idx = q * 256 + tid;
      const int row = idx >> 2;
      const int col = (idx & 3) * 8;
      gld_lds16(Bb + (long)row * K + col, (char*)(&Bs[buf][0]) + idx * 16);
    }
  };

  const int nt = K >> 5;
  int cur = 0;
  stage(0, 0);
  __syncthreads();
  for (int t = 0; t < nt; ++t) {
    if (t + 1 < nt) stage(cur ^ 1, (t + 1) << 5);
    bf16x8 af[MR], bfr[4];
#pragma unroll
    for (int i = 0; i < MR; ++i)
      af[i] = *(const bf16x8*)(&As[cur][0] + (wr * (BM / 2) + i * 16 + frow) * 32 + fk);
#pragma unroll
    for (int i = 0; i < 4; ++i)
      bfr[i] = *(const bf16x8*)(&Bs[cur][0] + (wc * 64 + i * 16 + frow) * 32 + fk);
#pragma unroll
    for (int im = 0; im < MR; ++im)
#pragma unroll
      for (int in = 0; in < 4; ++in)
        acc[im][in] = __builtin_amdgcn_mfma_f32_16x16x32_bf16(af[im], bfr[in],
                                                              acc[im][in], 0, 0, 0);
    __syncthreads();
    cur ^= 1;
  }

  const int crow0 = m0 + wr * (BM / 2) + (lane >> 4) * 4;
  const int ccol0 = n0 + wc * 64 + (lane & 15);
#pragma unroll
  for (int in = 0; in < 4; ++in) {
    const int col = ccol0 + in * 16;
    if (col >= Nreal) continue;
    const float bv = bias[col];
#pragma unroll
    for (int im = 0; im < MR; ++im) {
#pragma unroll
      for (int r = 0; r < 4; ++r) {
        const long row = crow0 + im * 16 + r;
        const float v = acc[im][in][r] + bv;
        if (EPI == 0) {
          ((float*)Cout)[row * Nreal + col] = v;
        } else if (EPI == 1) {
          ((__bf16*)Cout)[row * Nreal + col] = (__bf16)v;
        } else {
          const float gmul = 1.f / (1.f + __expf(-v)) + 0.1f;
          const long ix = row * Nreal + col;
          supR[ix] *= gmul;
          supI[ix] *= gmul;
        }
      }
    }
  }
}

// ---------------- LN (over 1024) + gelu -> bf16 ----------------
__global__ __launch_bounds__(256) void k_ln_gelu(const float* __restrict__ y,
                                                 const float* __restrict__ g,
                                                 const float* __restrict__ b,
                                                 __bf16* __restrict__ h) {
  __shared__ float scr[8];
  const int tid = threadIdx.x;
  const long row = blockIdx.x;
  const float* yr = y + row * 1024;
  f32x4 v = *(const f32x4*)(yr + tid * 4);
  float ls = v[0] + v[1] + v[2] + v[3];
  const float mu = block_sum(ls, scr) * (1.f / 1024.f);
  float lss = 0.f;
#pragma unroll
  for (int j = 0; j < 4; ++j) {
    const float d = v[j] - mu;
    lss += d * d;
  }
  const float var = block_sum(lss, scr) * (1.f / 1024.f);
  const float rstd = rsqrtf(var + 1e-5f);
  bf16x4 o;
#pragma unroll
  for (int j = 0; j < 4; ++j) {
    const int c = tid * 4 + j;
    const float t = (v[j] - mu) * rstd * g[c] + b[c];
    o[j] = (__bf16)gelu_fast(t);
  }
  *(bf16x4*)(h + row * 1024 + tid * 4) = o;
}

// ---------------- stage C ----------------
__global__ __launch_bounds__(256) void k_stage_c(
    const __bf16* __restrict__ outb, const float* __restrict__ ln_g,
    const float* __restrict__ ln_b, const float* __restrict__ phases,
    const float* __restrict__ temp, float* __restrict__ supr,
    float* __restrict__ supi, int b0) {
  __shared__ float wrs[3][1024];
  __shared__ float wis[3][1024];
  __shared__ float gbuf[2048];
  __shared__ float scr[8];
  const int tid = threadIdx.x;
  const long b = blockIdx.x;

#pragma unroll 1
  for (int s = 0; s < 3; ++s) {
    const __bf16* src = outb + b * 6144 + s * 2048;
    bf16x8 v8 = *(const bf16x8*)(src + tid * 8);
    float x[8];
#pragma unroll
    for (int j = 0; j < 8; ++j) x[j] = (float)v8[j];
    float ls = 0.f;
#pragma unroll
    for (int j = 0; j < 8; ++j) ls += x[j];
    const float mu = block_sum(ls, scr) * (1.f / 2048.f);
    float lss = 0.f;
#pragma unroll
    for (int j = 0; j < 8; ++j) {
      const float d = x[j] - mu;
      lss += d * d;
    }
    const float var = block_sum(lss, scr) * (1.f / 2048.f);
    const float rstd = rsqrtf(var + 1e-5f);
    const float* lg = ln_g + s * 2048;
    const float* lb = ln_b + s * 2048;
    float nsq = 0.f;
#pragma unroll
    for (int j = 0; j < 8; ++j) {
      const int e = tid * 8 + j;
      const float yv = (x[j] - mu) * rstd * lg[e] + lb[e];
      const float gv = __expf(-yv * yv);
      gbuf[e] = gv;
      nsq += gv * gv;
    }
    const float normsq = block_sum(nsq, scr) + 1e-8f;
    const float factor = sqrtf(2.25f / normsq);
    const float ph = phases[s];
    const float cs = cosf(ph), sn = sinf(ph);
#pragma unroll
    for (int j = 0; j < 4; ++j) {
      const int h = j * 256 + tid;
      const float a = gbuf[h] * factor;
      const float bb = gbuf[h + 1024] * factor;
      wrs[s][h] = a * cs - bb * sn;
      wis[s][h] = a * sn + bb * cs;
    }
    __syncthreads();
  }

  float mr[4];
  float pmn = 0.f;
#pragma unroll
  for (int j = 0; j < 4; ++j) {
    const int h = j * 256 + tid;
    const float m = (wrs[0][h] + wrs[1][h] + wrs[2][h]) * (1.f / 3.f);
    mr[j] = m;
    pmn += m * m;
  }
  const float mnorm = sqrtf(block_sum(pmn, scr)) + 1e-8f;
  float csim[3];
#pragma unroll 1
  for (int s = 0; s < 3; ++s) {
    float pd = 0.f, pw = 0.f;
#pragma unroll
    for (int j = 0; j < 4; ++j) {
      const int h = j * 256 + tid;
      const float w = wrs[s][h];
      pd += w * mr[j];
      pw += w * w;
    }
    const float dot = block_sum(pd, scr);
    const float wn = sqrtf(block_sum(pw, scr)) + 1e-8f;
    csim[s] = dot / (wn * mnorm);
  }
  const float T = temp[0];
  const float t0 = csim[0] / T, t1 = csim[1] / T, t2 = csim[2] / T;
  const float mx = fmaxf(t0, fmaxf(t1, t2));
  const float e0 = __expf(t0 - mx), e1 = __expf(t1 - mx), e2 = __expf(t2 - mx);
  const float inv = 1.f / (e0 + e1 + e2);
  const float w0 = e0 * inv, w1 = e1 * inv, w2 = e2 * inv;
#pragma unroll
  for (int j = 0; j < 4; ++j) {
    const int h = j * 256 + tid;
    supr[(long)(b0 + b) * 1024 + h] = wrs[0][h] * w0 + wrs[1][h] * w1 + wrs[2][h] * w2;
    supi[(long)(b0 + b) * 1024 + h] = wis[0][h] * w0 + wis[1][h] * w1 + wis[2][h] * w2;
  }
}

// ---------------- mag ----------------
__global__ __launch_bounds__(256) void k_mag(const float* __restrict__ sr,
                                             const float* __restrict__ si,
                                             __bf16* __restrict__ mag) {
  const long i = ((long)blockIdx.x * 256 + threadIdx.x) * 4;
  f32x4 r = *(const f32x4*)(sr + i);
  f32x4 im = *(const f32x4*)(si + i);
  bf16x4 o;
#pragma unroll
  for (int j = 0; j < 4; ++j)
    o[j] = (__bf16)sqrtf(r[j] * r[j] + im[j] * im[j] + 1e-8f);
  *(bf16x4*)(mag + i) = o;
}

// ---------------- fused top-8 (u64-key selection) + sparse cls1 ----------------
__global__ __launch_bounds__(256) void k_topk_cls1(
    const float* __restrict__ supr, const float* __restrict__ supi,
    const float* __restrict__ w1t, const float* __restrict__ b1,
    __bf16* __restrict__ hid) {
  __shared__ u64 candk[32];
  __shared__ u64 selk_s[8];
  __shared__ float ssum_s;
  const int tid = threadIdx.x;
  const int lane = tid & 63;
  const int wv = tid >> 6;
  const long b = blockIdx.x;

  f32x4 r = *(const f32x4*)(supr + b * 1024 + tid * 4);
  f32x4 im = *(const f32x4*)(supi + b * 1024 + tid * 4);
  u64 key[4];
#pragma unroll
  for (int j = 0; j < 4; ++j) {
    const float v = r[j] * r[j] + im[j] * im[j];
    key[j] = ((u64)__float_as_uint(v) << 32) | (unsigned)(~(unsigned)(tid * 4 + j));
  }
  u64 lm = key[0];
  int jm = 0;
#pragma unroll
  for (int j = 1; j < 4; ++j)
    if (key[j] > lm) { lm = key[j]; jm = j; }

#pragma unroll 1
  for (int it = 0; it < 8; ++it) {
    u64 bk = lm;
#pragma unroll
    for (int m = 1; m < 64; m <<= 1) {
      const u64 ok = __shfl_xor(bk, m, 64);
      bk = ok > bk ? ok : bk;
    }
    if (lane == 0) candk[wv * 8 + it] = bk;
    if (bk == lm) {
      key[jm] = 0ULL;
      lm = key[0]; jm = 0;
#pragma unroll
      for (int j = 1; j < 4; ++j)
        if (key[j] > lm) { lm = key[j]; jm = j; }
    }
  }
  __syncthreads();

  if (wv == 0) {
    u64 ck = (lane < 32) ? candk[lane] : 0ULL;
    float ss = 0.f;
#pragma unroll 1
    for (int it = 0; it < 8; ++it) {
      u64 bk = ck;
#pragma unroll
      for (int m = 1; m < 64; m <<= 1) {
        const u64 ok = __shfl_xor(bk, m, 64);
        bk = ok > bk ? ok : bk;
      }
      if (ck == bk) ck = 0ULL;
      if (lane == 0) {
        selk_s[it] = bk;
        ss += __uint_as_float((unsigned)(bk >> 32));
      }
    }
    if (lane == 0) ssum_s = ss;
  }
  __syncthreads();

  const float denom = 1.f / (ssum_s + 1e-8f);
  float p[8];
  int idx[8];
#pragma unroll
  for (int k = 0; k < 8; ++k) {
    const u64 kk = selk_s[k];
    p[k] = __uint_as_float((unsigned)(kk >> 32)) * denom;
    idx[k] = (int)(~(unsigned)kk & 1023u);
  }

  const int o0 = tid * 4;
  float acc0 = b1[o0], acc1 = b1[o0 + 1], acc2 = b1[o0 + 2], acc3 = b1[o0 + 3];
#pragma unroll
  for (int k = 0; k < 8; ++k) {
    const f32x4 wrow = *(const f32x4*)(w1t + (long)idx[k] * 1024 + o0);
    acc0 += p[k] * wrow[0];
    acc1 += p[k] * wrow[1];
    acc2 += p[k] * wrow[2];
    acc3 += p[k] * wrow[3];
  }
  bf16x4 o = {(__bf16)gelu_fast(acc0), (__bf16)gelu_fast(acc1),
              (__bf16)gelu_fast(acc2), (__bf16)gelu_fast(acc3)};
  *(bf16x4*)(hid + b * 1024 + o0) = o;
}

extern "C" void kernel_launch(void* const* d_in, const int* in_sizes, int n_in,
                              void* d_out, int out_size, void* d_ws, size_t ws_size,
                              hipStream_t stream) {
  const float* x      = (const float*)d_in[0];
  const float* proj_w = (const float*)d_in[1];
  const float* proj_b = (const float*)d_in[2];
  const float* ln_p_g = (const float*)d_in[3];
  const float* ln_p_b = (const float*)d_in[4];
  const float* wf_w   = (const float*)d_in[5];
  const float* wf_b   = (const float*)d_in[6];
  const float* ln_g   = (const float*)d_in[7];
  const float* ln_b   = (const float*)d_in[8];
  const float* temperature = (const float*)d_in[9];
  const float* phases = (const float*)d_in[10];
  const float* gate_w = (const float*)d_in[11];
  const float* gate_b = (const float*)d_in[12];
  const float* cls_w1 = (const float*)d_in[13];
  const float* cls_b1 = (const float*)d_in[14];
  const float* cls_w2 = (const float*)d_in[15];
  const float* cls_b2 = (const float*)d_in[16];
  float* out = (float*)d_out;
  (void)in_sizes; (void)n_in; (void)out_size;

  char* ws = (char*)d_ws;
  const size_t MB = 1024 * 1024;

  if (ws_size >= 196 * MB) {
    // ---- full layout (196MB) ----
    __bf16* xb   = (__bf16*)(ws + 0);
    float*  supr = (float*)(ws + 0);
    float*  y1   = (float*)(ws + 32 * MB);
    float*  supi = (float*)(ws + 32 * MB);
    __bf16* outb = (__bf16*)(ws + 64 * MB);
    __bf16* magb = (__bf16*)(ws + 64 * MB);
    __bf16* hid  = (__bf16*)(ws + 80 * MB);
    float*  w1t  = (float*)(ws + 96 * MB);
    __bf16* hb   = (__bf16*)(ws + 160 * MB);
    __bf16* wfwb = (__bf16*)(ws + 176 * MB);
    __bf16* gwb  = (__bf16*)(ws + 188 * MB);
    __bf16* c2b  = (__bf16*)(ws + 190 * MB);
    __bf16* w1b  = (__bf16*)(ws + 192 * MB);

    k_cast_bf16<<<16384, 256, 0, stream>>>(x, xb);
    k_cast_bf16<<<2048, 256, 0, stream>>>(proj_w, w1b);
    k_cast_bf16<<<6144, 256, 0, stream>>>(wf_w, wfwb);
    k_cast_bf16<<<1024, 256, 0, stream>>>(gate_w, gwb);
    k_cast_pad<<<1024, 256, 0, stream>>>(cls_w2, c2b, 1000, 1024);

    k_gemm_bt<0, 64><<<dim3(8, 128), 256, 0, stream>>>(xb, w1b, proj_b, y1, 8192, 1024, 2048, 1024, nullptr, nullptr);
    k_ln_gelu<<<8192, 256, 0, stream>>>(y1, ln_p_g, ln_p_b, hb);

    // G2 via 256x256 8-wave phase-interleaved kernel
    k_gemm256_bt<<<dim3(24, 32), 512, 0, stream>>>(hb, wfwb, wf_b, outb, 8192, 6144, 1024);
    k_stage_c<<<8192, 256, 0, stream>>>(outb, ln_g, ln_b, phases, temperature, supr, supi, 0);

    k_transpose1k<<<dim3(32, 32), 256, 0, stream>>>(cls_w1, w1t);
    for (int it = 0; it < 2; ++it) {
      k_mag<<<8192, 256, 0, stream>>>(supr, supi, magb);
      k_gemm_bt<4, 64><<<dim3(8, 128), 256, 0, stream>>>(magb, gwb, gate_b, nullptr, 8192, 1024, 1024, 1024, supr, supi);
    }
    k_topk_cls1<<<8192, 256, 0, stream>>>(supr, supi, w1t, cls_b1, hid);
    k_gemm_bt<0, 64><<<dim3(8, 128), 256, 0, stream>>>(hid, c2b, cls_b2, out, 8192, 1024, 1024, 1000, nullptr, nullptr);
  } else {
    // ---- fallback layout (128MB): proven 4-chunk path ----
    __bf16* xb    = (__bf16*)(ws + 0);
    float*  supr  = (float*)(ws + 0);
    float*  y1    = (float*)(ws + 32 * MB);
    __bf16* outc  = (__bf16*)(ws + 32 * MB);
    __bf16* magb  = (__bf16*)(ws + 32 * MB);
    __bf16* hid   = (__bf16*)(ws + 32 * MB);
    __bf16* w1b   = (__bf16*)(ws + 64 * MB);
    float*  supi  = (float*)(ws + 64 * MB);
    __bf16* wfwb  = (__bf16*)(ws + 96 * MB);
    __bf16* hb    = (__bf16*)(ws + 108 * MB);
    float*  w1t   = (float*)(ws + 108 * MB);
    __bf16* gwb   = (__bf16*)(ws + 124 * MB);
    __bf16* c2b   = (__bf16*)(ws + 126 * MB);

    k_cast_bf16<<<16384, 256, 0, stream>>>(x, xb);
    k_cast_bf16<<<2048, 256, 0, stream>>>(proj_w, w1b);
    k_cast_bf16<<<6144, 256, 0, stream>>>(wf_w, wfwb);
    k_cast_bf16<<<1024, 256, 0, stream>>>(gate_w, gwb);
    k_cast_pad<<<1024, 256, 0, stream>>>(cls_w2, c2b, 1000, 1024);

    k_gemm_bt<0, 64><<<dim3(8, 128), 256, 0, stream>>>(xb, w1b, proj_b, y1, 8192, 1024, 2048, 1024, nullptr, nullptr);
    k_ln_gelu<<<8192, 256, 0, stream>>>(y1, ln_p_g, ln_p_b, hb);

    for (int c = 0; c < 4; ++c) {
      k_gemm_bt<1, 128><<<dim3(48, 16), 256, 0, stream>>>(hb + (size_t)c * 2048 * 1024, wfwb, wf_b,
                                                          outc, 2048, 6144, 1024, 6144, nullptr, nullptr);
      k_stage_c<<<2048, 256, 0, stream>>>(outc, ln_g, ln_b, phases, temperature,
                                          supr, supi, c * 2048);
    }

    k_transpose1k<<<dim3(32, 32), 256, 0, stream>>>(cls_w1, w1t);
    for (int it = 0; it < 2; ++it) {
      k_mag<<<8192, 256, 0, stream>>>(supr, supi, magb);
      k_gemm_bt<4, 64><<<dim3(8, 128), 256, 0, stream>>>(magb, gwb, gate_b, nullptr, 8192, 1024, 1024, 1024, supr, supi);
    }
    k_topk_cls1<<<8192, 256, 0, stream>>>(supr, supi, w1t, cls_b1, hid);
    k_gemm_bt<0, 64><<<dim3(8, 128), 256, 0, stream>>>(hid, c2b, cls_b2, out, 8192, 1024, 1024, 1000, nullptr, nullptr);
  }
}